// Round 1
// baseline (357.039 us; speedup 1.0000x reference)
//
#include <hip/hip_runtime.h>
#include <hip/hip_cooperative_groups.h>

namespace cg = cooperative_groups;

// B=2, N=2048, E=32768, Fin=256, nhead=8, nhid=8 (C1=64), Fout=64. All f32.
#define BB    2
#define NN    2048
#define FIN   256
#define HH    8
#define NHID  8
#define C1    64
#define FOUT  64
#define MAXD  192    // fixed CSR row capacity (Poisson(16), max ~45)
#define FASTD 64     // fast-path cap for LDS score prefetch
#define NB    512    // cooperative grid: 512 blocks = 2 blocks/CU on 256 CUs

// ---------------------------------------------------------------------------
// Single cooperative kernel. 512 blocks x 256 thr (4 waves), 8 nodes/block,
// 2 nodes/wave. Phases separated by grid.sync():
//   P1: gemm1 (h1 = x@Wh, fused s1h/s2h) + edge scatter into fixed-stride CSR
//   P2: att1 + elu + gemm2 (h2, s1o, s2o); dedup writeback (b==0 blocks only)
//   P3: att2 -> v kept in REGISTERS; per-block (m,s) LSE partials
//   P4: merge partials -> lse[b*64+o] (128 rows, blocks 0..127)
//   P5: out[b][n][o] = v - lse   (fully coalesced 256B stores)
// out2T intermediate is gone entirely (was 2x 16x-amplified scatter paths).
__global__ __launch_bounds__(256, 2)
void k_gat(const float* __restrict__ x, const float* __restrict__ Wh,
           const float* __restrict__ ah, const float* __restrict__ bh,
           const float* __restrict__ Wo, const float* __restrict__ ao,
           const float* __restrict__ bo, const int* __restrict__ edges, int E,
           float* __restrict__ h1, float* __restrict__ s1h, float* __restrict__ s2h,
           int* __restrict__ cnt, int* __restrict__ csr,
           float* __restrict__ h2, float* __restrict__ s1o, float* __restrict__ s2o,
           float* __restrict__ pm, float* __restrict__ ps, float* __restrict__ lse,
           float* __restrict__ out)
{
    cg::grid_group grid = cg::this_grid();

    // LDS union: 12 KB max -> 2 blocks/CU co-residency is LDS-safe (24 KB/CU).
    __shared__ union SMem {
        float xs1[8][FIN];                                            // P1: 8 KB
        struct { int tg[4][MAXD]; float es[4][FASTD][HH]; float xsg[4][C1]; } p2;  // 12 KB
        struct { int tg[4][MAXD]; float es[4][FASTD]; float vals[8][C1]; } p3;     // 6 KB
    } sm;

    int tid = threadIdx.x, w = tid >> 6, lane = tid & 63;
    int bb = blockIdx.x >> 8;            // batch of this block (256 blocks per b)

    // ---------------- P1: gemm1 + edge scatter -----------------------------
    {
        int base = blockIdx.x * 8;
        const float4* xv = (const float4*)(x + (size_t)base * FIN);
        float4* xsv = (float4*)&sm.xs1[0][0];
        xsv[tid] = xv[tid];
        xsv[tid + 256] = xv[tid + 256];

        // this block's slice of the edge list (cnt zeroed by prior memset)
        int epb = (E + NB - 1) / NB;
        int e0 = blockIdx.x * epb;
        int e1 = e0 + epb; if (e1 > E) e1 = E;
        for (int e = e0 + tid; e < e1; e += 256) {
            int s = edges[e], t = edges[E + e];
            int pos = atomicAdd(&cnt[s], 1);
            if (pos < MAXD) csr[s * MAXD + pos] = t;
        }
        __syncthreads();

        int head = lane >> 3, k = lane & 7;
        const float* Wp = Wh + head * FIN * NHID + k;
        int n0 = w * 2;
        const float4* xr0 = (const float4*)sm.xs1[n0 + 0];
        const float4* xr1 = (const float4*)sm.xs1[n0 + 1];
        float a0 = 0.f, a1 = 0.f;
#pragma unroll 8
        for (int ff = 0; ff < FIN / 4; ++ff) {
            float4 v0 = xr0[ff], v1 = xr1[ff];
            float w0 = Wp[(4 * ff + 0) * NHID];
            float w1 = Wp[(4 * ff + 1) * NHID];
            float w2 = Wp[(4 * ff + 2) * NHID];
            float w3 = Wp[(4 * ff + 3) * NHID];
            a0 += w0 * v0.x; a0 += w1 * v0.y; a0 += w2 * v0.z; a0 += w3 * v0.w;
            a1 += w0 * v1.x; a1 += w1 * v1.y; a1 += w2 * v1.z; a1 += w3 * v1.w;
        }
        size_t hb = (size_t)(base + n0) * C1 + lane;
        h1[hb] = a0; h1[hb + C1] = a1;

        float c1 = ah[head * 16 + k], c2 = ah[head * 16 + 8 + k];
        float p0 = a0 * c1, p1 = a1 * c1;
        float q0 = a0 * c2, q1 = a1 * c2;
        for (int o = 1; o < 8; o <<= 1) {
            p0 += __shfl_xor(p0, o); p1 += __shfl_xor(p1, o);
            q0 += __shfl_xor(q0, o); q1 += __shfl_xor(q1, o);
        }
        if (k == 0) {
            size_t bn0 = (size_t)(base + n0);
            s1h[bn0 * HH + head] = p0;       s2h[bn0 * HH + head] = q0;
            s1h[(bn0 + 1) * HH + head] = p1; s2h[(bn0 + 1) * HH + head] = q1;
        }
    }
    grid.sync();

    // ---------------- P2: att1 + elu + gemm2 -------------------------------
    {
        int* tg = sm.p2.tg[w];
        float* xs = sm.p2.xsg[w];
        int head = lane >> 3;
#pragma unroll 2
        for (int j = 0; j < 2; ++j) {
            int bn = blockIdx.x * 8 + w * 2 + j;
            int b = bn >> 11, n = bn & (NN - 1);

            int d = cnt[n]; if (d > MAXD) d = MAXD;
            for (int l = lane; l < d; l += 64) tg[l] = csr[n * MAXD + l];
            // dedup: first occurrence kept; later dups -> -1
            for (int l = lane; l < d; l += 64) {
                int t = tg[l], f = 0;
                for (int jj = 0; jj < l; ++jj) f |= (tg[jj] == t);
                if (f) tg[l] = -1;
            }
            // single-writer deduped-row writeback (b==0 blocks only)
            if (b == 0)
                for (int l = lane; l < d; l += 64) csr[n * MAXD + l] = tg[l];

            const float* hp = h1 + (size_t)b * NN * C1 + lane;
            float outv;
            if (d == 0) {   // dense -1e20 row -> uniform softmax over all N
                float acc = 0.f;
                for (int jj = 0; jj < NN; ++jj) acc += hp[(size_t)jj * C1];
                outv = acc * (1.0f / NN);
            } else if (d <= FASTD) {
                const float* s2b = s2h + (size_t)b * NN * HH;
                for (int idx = lane; idx < d * HH; idx += 64) {
                    int l = idx >> 3, hh = idx & 7;
                    int t = tg[l];
                    sm.p2.es[w][l][hh] = s2b[(size_t)(t < 0 ? 0 : t) * HH + hh];
                }
                float s1 = s1h[(size_t)bn * HH + head];
                float m = -3.4e38f;
                for (int p = 0; p < d; ++p) {
                    float ee = s1 + sm.p2.es[w][p][head];
                    ee = ee > 0.f ? ee : 0.2f * ee;
                    m = fmaxf(m, tg[p] < 0 ? -3.4e38f : ee);
                }
                float den = 0.f, acc = 0.f;
                int p = 0;
                for (; p + 4 <= d; p += 4) {
                    int t0 = tg[p], t1 = tg[p + 1], t2 = tg[p + 2], t3 = tg[p + 3];
                    float v0 = hp[(size_t)(t0 < 0 ? 0 : t0) * C1];
                    float v1 = hp[(size_t)(t1 < 0 ? 0 : t1) * C1];
                    float v2 = hp[(size_t)(t2 < 0 ? 0 : t2) * C1];
                    float v3 = hp[(size_t)(t3 < 0 ? 0 : t3) * C1];
                    float e0 = s1 + sm.p2.es[w][p + 0][head]; e0 = e0 > 0.f ? e0 : 0.2f * e0;
                    float e1 = s1 + sm.p2.es[w][p + 1][head]; e1 = e1 > 0.f ? e1 : 0.2f * e1;
                    float e2 = s1 + sm.p2.es[w][p + 2][head]; e2 = e2 > 0.f ? e2 : 0.2f * e2;
                    float e3 = s1 + sm.p2.es[w][p + 3][head]; e3 = e3 > 0.f ? e3 : 0.2f * e3;
                    float w0 = t0 < 0 ? 0.f : expf(e0 - m);
                    float w1 = t1 < 0 ? 0.f : expf(e1 - m);
                    float w2 = t2 < 0 ? 0.f : expf(e2 - m);
                    float w3 = t3 < 0 ? 0.f : expf(e3 - m);
                    den += w0; acc += w0 * v0;
                    den += w1; acc += w1 * v1;
                    den += w2; acc += w2 * v2;
                    den += w3; acc += w3 * v3;
                }
                for (; p < d; ++p) {
                    int t = tg[p];
                    float v = hp[(size_t)(t < 0 ? 0 : t) * C1];
                    float ee = s1 + sm.p2.es[w][p][head];
                    ee = ee > 0.f ? ee : 0.2f * ee;
                    float wt = t < 0 ? 0.f : expf(ee - m);
                    den += wt; acc += wt * v;
                }
                outv = acc / den;
            } else {
                // slow fallback (statistically unreachable)
                float s1 = s1h[(size_t)bn * HH + head];
                const float* s2b = s2h + (size_t)b * NN * HH;
                float m = -3.4e38f;
                for (int p = 0; p < d; ++p) {
                    int t = tg[p]; if (t < 0) continue;
                    float ee = s1 + s2b[(size_t)t * HH + head];
                    ee = ee > 0.f ? ee : 0.2f * ee;
                    m = fmaxf(m, ee);
                }
                float den = 0.f, acc = 0.f;
                for (int p = 0; p < d; ++p) {
                    int t = tg[p]; if (t < 0) continue;
                    float ee = s1 + s2b[(size_t)t * HH + head];
                    ee = ee > 0.f ? ee : 0.2f * ee;
                    float wt = expf(ee - m);
                    den += wt;
                    acc += wt * hp[(size_t)t * C1];
                }
                outv = acc / den;
            }
            outv += bh[lane];
            xs[lane] = outv > 0.f ? outv : (expf(outv) - 1.f);   // elu

            float acc2 = 0.f;
#pragma unroll 16
            for (int f = 0; f < C1; ++f) acc2 += xs[f] * Wo[f * FOUT + lane];
            h2[(size_t)bn * FOUT + lane] = acc2;
            float p = acc2 * ao[lane];
            float q = acc2 * ao[FOUT + lane];
            for (int o = 1; o < 64; o <<= 1) { p += __shfl_xor(p, o); q += __shfl_xor(q, o); }
            if (lane == 0) { s1o[bn] = p; s2o[bn] = q; }
        }
    }
    grid.sync();

    // ---------------- P3: att2 -> v in regs + block LSE partials -----------
    float v01[2];
    {
        int* tg = sm.p3.tg[w];
#pragma unroll 2
        for (int j = 0; j < 2; ++j) {
            int bn = blockIdx.x * 8 + w * 2 + j;
            int b = bn >> 11, n = bn & (NN - 1);

            int d = cnt[n]; if (d > MAXD) d = MAXD;
            for (int l = lane; l < d; l += 64) tg[l] = csr[n * MAXD + l];

            const float* hp = h2 + (size_t)b * NN * FOUT + lane;
            const float* s2p = s2o + b * NN;
            float outv;
            if (d == 0) {
                float acc = 0.f;
                for (int jj = 0; jj < NN; ++jj) acc += hp[(size_t)jj * FOUT];
                outv = acc * (1.0f / NN);
            } else if (d <= FASTD) {
                for (int l = lane; l < d; l += 64) {
                    int t = tg[l];
                    sm.p3.es[w][l] = s2p[t < 0 ? 0 : t];
                }
                float s1 = s1o[bn];
                float m = -3.4e38f;
                for (int p = 0; p < d; ++p) {
                    float ee = s1 + sm.p3.es[w][p];
                    ee = ee > 0.f ? ee : 0.2f * ee;
                    m = fmaxf(m, tg[p] < 0 ? -3.4e38f : ee);
                }
                float den = 0.f, acc = 0.f;
                int p = 0;
                for (; p + 4 <= d; p += 4) {
                    int t0 = tg[p], t1 = tg[p + 1], t2 = tg[p + 2], t3 = tg[p + 3];
                    float v0 = hp[(size_t)(t0 < 0 ? 0 : t0) * FOUT];
                    float v1 = hp[(size_t)(t1 < 0 ? 0 : t1) * FOUT];
                    float v2 = hp[(size_t)(t2 < 0 ? 0 : t2) * FOUT];
                    float v3 = hp[(size_t)(t3 < 0 ? 0 : t3) * FOUT];
                    float e0 = s1 + sm.p3.es[w][p + 0]; e0 = e0 > 0.f ? e0 : 0.2f * e0;
                    float e1 = s1 + sm.p3.es[w][p + 1]; e1 = e1 > 0.f ? e1 : 0.2f * e1;
                    float e2 = s1 + sm.p3.es[w][p + 2]; e2 = e2 > 0.f ? e2 : 0.2f * e2;
                    float e3 = s1 + sm.p3.es[w][p + 3]; e3 = e3 > 0.f ? e3 : 0.2f * e3;
                    float w0 = t0 < 0 ? 0.f : expf(e0 - m);
                    float w1 = t1 < 0 ? 0.f : expf(e1 - m);
                    float w2 = t2 < 0 ? 0.f : expf(e2 - m);
                    float w3 = t3 < 0 ? 0.f : expf(e3 - m);
                    den += w0; acc += w0 * v0;
                    den += w1; acc += w1 * v1;
                    den += w2; acc += w2 * v2;
                    den += w3; acc += w3 * v3;
                }
                for (; p < d; ++p) {
                    int t = tg[p];
                    float v = hp[(size_t)(t < 0 ? 0 : t) * FOUT];
                    float ee = s1 + sm.p3.es[w][p];
                    ee = ee > 0.f ? ee : 0.2f * ee;
                    float wt = t < 0 ? 0.f : expf(ee - m);
                    den += wt; acc += wt * v;
                }
                outv = acc / den;
            } else {
                float s1 = s1o[bn];
                float m = -3.4e38f;
                for (int p = 0; p < d; ++p) {
                    int t = tg[p]; if (t < 0) continue;
                    float ee = s1 + s2p[t];
                    ee = ee > 0.f ? ee : 0.2f * ee;
                    m = fmaxf(m, ee);
                }
                float den = 0.f, acc = 0.f;
                for (int p = 0; p < d; ++p) {
                    int t = tg[p]; if (t < 0) continue;
                    float ee = s1 + s2p[t];
                    ee = ee > 0.f ? ee : 0.2f * ee;
                    float wt = expf(ee - m);
                    den += wt;
                    acc += wt * hp[(size_t)t * FOUT];
                }
                outv = acc / den;
            }
            v01[j] = outv + bo[lane];
        }

        sm.p3.vals[w * 2 + 0][lane] = v01[0];
        sm.p3.vals[w * 2 + 1][lane] = v01[1];
        __syncthreads();
        if (w == 0) {   // per-block (m,s) partial over its 8 nodes, per o=lane
            float m = -3.4e38f;
#pragma unroll
            for (int i = 0; i < 8; ++i) m = fmaxf(m, sm.p3.vals[i][lane]);
            float s = 0.f;
#pragma unroll
            for (int i = 0; i < 8; ++i) s += expf(sm.p3.vals[i][lane] - m);
            int c = blockIdx.x & 255;                     // chunk within batch
            size_t r = (size_t)(bb * FOUT + lane);        // row = b*64+o
            pm[r * 256 + c] = m;
            ps[r * 256 + c] = s;
        }
    }
    grid.sync();

    // ---------------- P4: merge partials -> lse[128] -----------------------
    if (blockIdx.x < BB * FOUT && w == 0) {
        size_t r = blockIdx.x;
        float mv[4], sv[4];
        float M = -3.4e38f;
#pragma unroll
        for (int i = 0; i < 4; ++i) {
            mv[i] = pm[r * 256 + lane + 64 * i];
            sv[i] = ps[r * 256 + lane + 64 * i];
            M = fmaxf(M, mv[i]);
        }
        for (int o = 1; o < 64; o <<= 1) M = fmaxf(M, __shfl_xor(M, o));
        float S = 0.f;
#pragma unroll
        for (int i = 0; i < 4; ++i) S += sv[i] * expf(mv[i] - M);
        for (int o = 1; o < 64; o <<= 1) S += __shfl_xor(S, o);
        if (lane == 0) lse[r] = M + logf(S);
    }
    grid.sync();

    // ---------------- P5: coalesced out = v - lse --------------------------
    {
        float l0 = lse[bb * FOUT + lane];
        size_t bn0 = (size_t)blockIdx.x * 8 + w * 2;
        out[bn0 * FOUT + lane] = v01[0] - l0;
        out[(bn0 + 1) * FOUT + lane] = v01[1] - l0;
    }
}

// ---------------------------------------------------------------------------
extern "C" void kernel_launch(void* const* d_in, const int* in_sizes, int n_in,
                              void* d_out, int out_size, void* d_ws, size_t ws_size,
                              hipStream_t stream)
{
    (void)n_in; (void)out_size; (void)ws_size;
    const float* x     = (const float*)d_in[0];
    const int*   edges = (const int*)d_in[1];
    const float* Wh    = (const float*)d_in[2];
    const float* ah    = (const float*)d_in[3];
    const float* bh    = (const float*)d_in[4];
    const float* Wo    = (const float*)d_in[5];
    const float* ao    = (const float*)d_in[6];
    const float* bo    = (const float*)d_in[7];
    int E = in_sizes[1] / 2;
    float* outp = (float*)d_out;

    char* w = (char*)d_ws;
    float* h1  = (float*)w; w += (size_t)BB * NN * C1 * 4;      // 1 MB
    float* s1h = (float*)w; w += (size_t)BB * NN * HH * 4;      // 128 KB
    float* s2h = (float*)w; w += (size_t)BB * NN * HH * 4;      // 128 KB
    float* h2  = (float*)w; w += (size_t)BB * NN * FOUT * 4;    // 1 MB
    float* s1o = (float*)w; w += (size_t)BB * NN * 4;
    float* s2o = (float*)w; w += (size_t)BB * NN * 4;
    float* pm  = (float*)w; w += (size_t)BB * FOUT * 256 * 4;   // 128 KB
    float* ps  = (float*)w; w += (size_t)BB * FOUT * 256 * 4;   // 128 KB
    float* lse = (float*)w; w += 4096;                          // 512 B used
    int*   cnt = (int*)w;   w += (size_t)NN * 4;
    int*   csr = (int*)w;   w += (size_t)NN * MAXD * 4;         // 1.5 MB

    hipMemsetAsync(cnt, 0, (size_t)NN * 4, stream);

    void* args[] = {(void*)&x, (void*)&Wh, (void*)&ah, (void*)&bh,
                    (void*)&Wo, (void*)&ao, (void*)&bo, (void*)&edges, (void*)&E,
                    (void*)&h1, (void*)&s1h, (void*)&s2h, (void*)&cnt, (void*)&csr,
                    (void*)&h2, (void*)&s1o, (void*)&s2o,
                    (void*)&pm, (void*)&ps, (void*)&lse, (void*)&outp};
    hipLaunchCooperativeKernel(reinterpret_cast<const void*>(k_gat),
                               dim3(NB), dim3(256), args, 0u, stream);
}

// Round 2
// 111.824 us; speedup vs baseline: 3.1929x; 3.1929x over previous
//
#include <hip/hip_runtime.h>

// B=2, N=2048, E=32768, Fin=256, nhead=8, nhid=8 (C1=64), Fout=64. All f32.
#define BB    2
#define NN    2048
#define FIN   256
#define HH    8
#define NHID  8
#define C1    64
#define FOUT  64
#define MAXD  192    // fixed CSR row capacity (Poisson(16), max ~45)
#define FASTD 64     // fast-path cap for LDS score prefetch
#define GB1   512    // gemm1 blocks (8 nodes each)
#define CHUNK 512    // LSE partial chunks per batch (= k_att2b blocks per b)

// ---------------------------------------------------------------------------
// K1 "front": blocks 0..GB1-1 = gemm1 (h1 = x @ W_h, fused s1/s2, 8 nodes/blk,
//             2 nodes/wave); blocks GB1.. = edge scatter into fixed-stride CSR.
// cnt[] is zeroed by a preceding hipMemsetAsync (stream-ordered).
__global__ __launch_bounds__(256)
void k_front(const float* __restrict__ x, const float* __restrict__ Wh,
             const float* __restrict__ ah, const int* __restrict__ edges, int E,
             float* __restrict__ h1, float* __restrict__ s1h, float* __restrict__ s2h,
             int* __restrict__ cnt, int* __restrict__ csr)
{
    __shared__ float xs[8][FIN];   // 8 KB (unused by scatter blocks)
    int tid = threadIdx.x;

    if (blockIdx.x >= GB1) {
        int e = (blockIdx.x - GB1) * 256 + tid;
        if (e < E) {
            int s = edges[e], t = edges[E + e];
            int pos = atomicAdd(&cnt[s], 1);
            if (pos < MAXD) csr[s * MAXD + pos] = t;
        }
        return;
    }

    // ---- gemm1: 8 nodes/block, 2 nodes/wave ----
    int base = blockIdx.x * 8;
    const float4* xv = (const float4*)(x + (size_t)base * FIN);
    float4* xsv = (float4*)&xs[0][0];
    xsv[tid] = xv[tid];
    xsv[tid + 256] = xv[tid + 256];
    __syncthreads();

    int wave = tid >> 6, lane = tid & 63;
    int head = lane >> 3, k = lane & 7;
    const float* Wp = Wh + head * FIN * NHID + k;
    int n0 = wave * 2;
    const float4* xr0 = (const float4*)xs[n0 + 0];
    const float4* xr1 = (const float4*)xs[n0 + 1];
    float a0 = 0.f, a1 = 0.f;
#pragma unroll 8
    for (int ff = 0; ff < FIN / 4; ++ff) {
        float4 v0 = xr0[ff], v1 = xr1[ff];
        float w0 = Wp[(4 * ff + 0) * NHID];
        float w1 = Wp[(4 * ff + 1) * NHID];
        float w2 = Wp[(4 * ff + 2) * NHID];
        float w3 = Wp[(4 * ff + 3) * NHID];
        a0 += w0 * v0.x; a0 += w1 * v0.y; a0 += w2 * v0.z; a0 += w3 * v0.w;
        a1 += w0 * v1.x; a1 += w1 * v1.y; a1 += w2 * v1.z; a1 += w3 * v1.w;
    }
    size_t hb = (size_t)(base + n0) * C1 + lane;
    h1[hb] = a0; h1[hb + C1] = a1;

    float c1 = ah[head * 16 + k], c2 = ah[head * 16 + 8 + k];
    float p0 = a0 * c1, p1 = a1 * c1;
    float q0 = a0 * c2, q1 = a1 * c2;
    for (int o = 1; o < 8; o <<= 1) {
        p0 += __shfl_xor(p0, o); p1 += __shfl_xor(p1, o);
        q0 += __shfl_xor(q0, o); q1 += __shfl_xor(q1, o);
    }
    if (k == 0) {
        float psv[2] = {p0, p1}, qsv[2] = {q0, q1};
#pragma unroll
        for (int j = 0; j < 2; ++j) {
            int bn = base + n0 + j;
            s1h[(size_t)bn * HH + head] = psv[j];
            s2h[(size_t)bn * HH + head] = qsv[j];
        }
    }
}

// ---------------------------------------------------------------------------
// K2: layer-1 sparse attention + elu + gemm2 + s1o/s2o. 4 nodes/block,
// one wave per node, wave-private LDS, no __syncthreads.
// Dedup marks later duplicates -1 and WRITES BACK to csr (att2 skips dedup).
__global__ __launch_bounds__(256)
void k_att1g2(const float* __restrict__ h1, const float* __restrict__ s1h,
              const float* __restrict__ s2h, const float* __restrict__ bh,
              const int* __restrict__ cnt, int* __restrict__ csr,
              const float* __restrict__ Wo, const float* __restrict__ ao,
              float* __restrict__ h2, float* __restrict__ s1o, float* __restrict__ s2o)
{
    __shared__ int tg4[4][MAXD];
    __shared__ float es4[4][FASTD][HH];   // 8 KB
    __shared__ float xs4[4][C1];
    int tid = threadIdx.x, w = tid >> 6, lane = tid & 63;
    int* tg = tg4[w];
    float* xs = xs4[w];
    int bn = blockIdx.x * 4 + w;
    int b = bn >> 11, n = bn & (NN - 1);
    int head = lane >> 3;

    int d = cnt[n]; if (d > MAXD) d = MAXD;
    for (int l = lane; l < d; l += 64) tg[l] = csr[n * MAXD + l];
    // dedup: first occurrence kept; later dups -> -1
    for (int l = lane; l < d; l += 64) {
        int t = tg[l], f = 0;
        for (int j = 0; j < l; ++j) f |= (tg[j] == t);
        if (f) tg[l] = -1;
    }
    // write back deduped row so att2 can skip its dedup pass (benign dup write)
    for (int l = lane; l < d; l += 64) csr[n * MAXD + l] = tg[l];

    const float* hp = h1 + (size_t)b * NN * C1 + lane;
    float out;
    if (d == 0) {   // dense -1e20 row -> uniform softmax over all N
        float acc = 0.f;
        for (int j = 0; j < NN; ++j) acc += hp[(size_t)j * C1];
        out = acc * (1.0f / NN);
    } else if (d <= FASTD) {
        // prefetch s2 scores: contiguous 8 floats per edge (coalesced)
        const float* s2b = s2h + (size_t)b * NN * HH;
        for (int idx = lane; idx < d * HH; idx += 64) {
            int l = idx >> 3, hh = idx & 7;
            int t = tg[l];
            es4[w][l][hh] = s2b[(size_t)(t < 0 ? 0 : t) * HH + hh];
        }
        float s1 = s1h[(size_t)bn * HH + head];
        float m = -3.4e38f;
        for (int p = 0; p < d; ++p) {
            float ee = s1 + es4[w][p][head];
            ee = ee > 0.f ? ee : 0.2f * ee;
            m = fmaxf(m, tg[p] < 0 ? -3.4e38f : ee);
        }
        float den = 0.f, acc = 0.f;
        int p = 0;
        for (; p + 4 <= d; p += 4) {
            int t0 = tg[p], t1 = tg[p + 1], t2 = tg[p + 2], t3 = tg[p + 3];
            float v0 = hp[(size_t)(t0 < 0 ? 0 : t0) * C1];
            float v1 = hp[(size_t)(t1 < 0 ? 0 : t1) * C1];
            float v2 = hp[(size_t)(t2 < 0 ? 0 : t2) * C1];
            float v3 = hp[(size_t)(t3 < 0 ? 0 : t3) * C1];
            float e0 = s1 + es4[w][p + 0][head]; e0 = e0 > 0.f ? e0 : 0.2f * e0;
            float e1 = s1 + es4[w][p + 1][head]; e1 = e1 > 0.f ? e1 : 0.2f * e1;
            float e2 = s1 + es4[w][p + 2][head]; e2 = e2 > 0.f ? e2 : 0.2f * e2;
            float e3 = s1 + es4[w][p + 3][head]; e3 = e3 > 0.f ? e3 : 0.2f * e3;
            float w0 = t0 < 0 ? 0.f : expf(e0 - m);
            float w1 = t1 < 0 ? 0.f : expf(e1 - m);
            float w2 = t2 < 0 ? 0.f : expf(e2 - m);
            float w3 = t3 < 0 ? 0.f : expf(e3 - m);
            den += w0; acc += w0 * v0;
            den += w1; acc += w1 * v1;
            den += w2; acc += w2 * v2;
            den += w3; acc += w3 * v3;
        }
        for (; p < d; ++p) {
            int t = tg[p];
            float v = hp[(size_t)(t < 0 ? 0 : t) * C1];
            float ee = s1 + es4[w][p][head];
            ee = ee > 0.f ? ee : 0.2f * ee;
            float wt = t < 0 ? 0.f : expf(ee - m);
            den += wt; acc += wt * v;
        }
        out = acc / den;
    } else {
        // slow fallback (statistically unreachable)
        float s1 = s1h[(size_t)bn * HH + head];
        const float* s2b = s2h + (size_t)b * NN * HH;
        float m = -3.4e38f;
        for (int p = 0; p < d; ++p) {
            int t = tg[p]; if (t < 0) continue;
            float ee = s1 + s2b[(size_t)t * HH + head];
            ee = ee > 0.f ? ee : 0.2f * ee;
            m = fmaxf(m, ee);
        }
        float den = 0.f, acc = 0.f;
        for (int p = 0; p < d; ++p) {
            int t = tg[p]; if (t < 0) continue;
            float ee = s1 + s2b[(size_t)t * HH + head];
            ee = ee > 0.f ? ee : 0.2f * ee;
            float wt = expf(ee - m);
            den += wt;
            acc += wt * hp[(size_t)t * C1];
        }
        out = acc / den;
    }
    out += bh[lane];
    xs[lane] = out > 0.f ? out : (expf(out) - 1.f);   // elu

    // gemm2 within the same wave (xs is wave-private)
    float acc2 = 0.f;
#pragma unroll 16
    for (int f = 0; f < C1; ++f) acc2 += xs[f] * Wo[f * FOUT + lane];
    h2[(size_t)bn * FOUT + lane] = acc2;
    float p = acc2 * ao[lane];
    float q = acc2 * ao[FOUT + lane];
    for (int o = 1; o < 64; o <<= 1) { p += __shfl_xor(p, o); q += __shfl_xor(q, o); }
    if (lane == 0) { s1o[bn] = p; s2o[bn] = q; }
}

// ---------------------------------------------------------------------------
// K3: layer-2 sparse attention -> COALESCED out2[bn][o] (+bias), plus
// per-block LSE partials: for each o, (m,s) over this block's 4 nodes.
// pm/ps layout: [chunk][row] with row = b*FOUT+o -> 256B coalesced stores.
__global__ __launch_bounds__(256)
void k_att2b(const float* __restrict__ h2, const float* __restrict__ s1o,
             const float* __restrict__ s2o, const float* __restrict__ bo,
             const int* __restrict__ cnt, const int* __restrict__ csr,
             float* __restrict__ out2, float* __restrict__ pm, float* __restrict__ ps)
{
    __shared__ int tg4[4][MAXD];
    __shared__ float es4[4][FASTD];
    __shared__ float vals[4][C1];
    int tid = threadIdx.x, w = tid >> 6, lane = tid & 63;
    int* tg = tg4[w];
    int bn = blockIdx.x * 4 + w;
    int b = bn >> 11, n = bn & (NN - 1);

    int d = cnt[n]; if (d > MAXD) d = MAXD;
    for (int l = lane; l < d; l += 64) tg[l] = csr[n * MAXD + l];

    const float* hp = h2 + (size_t)b * NN * FOUT + lane;
    const float* s2p = s2o + b * NN;
    float out;
    if (d == 0) {
        float acc = 0.f;
        for (int j = 0; j < NN; ++j) acc += hp[(size_t)j * FOUT];
        out = acc * (1.0f / NN);
    } else if (d <= FASTD) {
        for (int l = lane; l < d; l += 64) {
            int t = tg[l];
            es4[w][l] = s2p[t < 0 ? 0 : t];
        }
        float s1 = s1o[bn];
        float m = -3.4e38f;
        for (int p = 0; p < d; ++p) {
            float ee = s1 + es4[w][p];
            ee = ee > 0.f ? ee : 0.2f * ee;
            m = fmaxf(m, tg[p] < 0 ? -3.4e38f : ee);
        }
        float den = 0.f, acc = 0.f;
        int p = 0;
        for (; p + 4 <= d; p += 4) {
            int t0 = tg[p], t1 = tg[p + 1], t2 = tg[p + 2], t3 = tg[p + 3];
            float v0 = hp[(size_t)(t0 < 0 ? 0 : t0) * FOUT];
            float v1 = hp[(size_t)(t1 < 0 ? 0 : t1) * FOUT];
            float v2 = hp[(size_t)(t2 < 0 ? 0 : t2) * FOUT];
            float v3 = hp[(size_t)(t3 < 0 ? 0 : t3) * FOUT];
            float e0 = s1 + es4[w][p + 0]; e0 = e0 > 0.f ? e0 : 0.2f * e0;
            float e1 = s1 + es4[w][p + 1]; e1 = e1 > 0.f ? e1 : 0.2f * e1;
            float e2 = s1 + es4[w][p + 2]; e2 = e2 > 0.f ? e2 : 0.2f * e2;
            float e3 = s1 + es4[w][p + 3]; e3 = e3 > 0.f ? e3 : 0.2f * e3;
            float w0 = t0 < 0 ? 0.f : expf(e0 - m);
            float w1 = t1 < 0 ? 0.f : expf(e1 - m);
            float w2 = t2 < 0 ? 0.f : expf(e2 - m);
            float w3 = t3 < 0 ? 0.f : expf(e3 - m);
            den += w0; acc += w0 * v0;
            den += w1; acc += w1 * v1;
            den += w2; acc += w2 * v2;
            den += w3; acc += w3 * v3;
        }
        for (; p < d; ++p) {
            int t = tg[p];
            float v = hp[(size_t)(t < 0 ? 0 : t) * FOUT];
            float ee = s1 + es4[w][p];
            ee = ee > 0.f ? ee : 0.2f * ee;
            float wt = t < 0 ? 0.f : expf(ee - m);
            den += wt; acc += wt * v;
        }
        out = acc / den;
    } else {
        float s1 = s1o[bn];
        float m = -3.4e38f;
        for (int p = 0; p < d; ++p) {
            int t = tg[p]; if (t < 0) continue;
            float ee = s1 + s2p[t];
            ee = ee > 0.f ? ee : 0.2f * ee;
            m = fmaxf(m, ee);
        }
        float den = 0.f, acc = 0.f;
        for (int p = 0; p < d; ++p) {
            int t = tg[p]; if (t < 0) continue;
            float ee = s1 + s2p[t];
            ee = ee > 0.f ? ee : 0.2f * ee;
            float wt = expf(ee - m);
            den += wt;
            acc += wt * hp[(size_t)t * FOUT];
        }
        out = acc / den;
    }
    float v = out + bo[lane];
    out2[(size_t)bn * FOUT + lane] = v;     // coalesced 256B/wave
    vals[w][lane] = v;
    __syncthreads();
    if (w == 0) {   // per-block (m,s) partial over its 4 nodes, per o=lane
        float m = -3.4e38f;
#pragma unroll
        for (int i = 0; i < 4; ++i) m = fmaxf(m, vals[i][lane]);
        float s = 0.f;
#pragma unroll
        for (int i = 0; i < 4; ++i) s += expf(vals[i][lane] - m);
        int c = blockIdx.x & (CHUNK - 1);       // chunk within batch
        int r = b * FOUT + lane;                // row = b*64+o
        pm[c * (BB * FOUT) + r] = m;            // coalesced
        ps[c * (BB * FOUT) + r] = s;
    }
}

// ---------------------------------------------------------------------------
// K4: merge 512 chunk partials per row -> lse[b*64+o]. grid = 128 blocks.
__global__ __launch_bounds__(256)
void k_merge(const float* __restrict__ pm, const float* __restrict__ ps,
             float* __restrict__ lse)
{
    int r = blockIdx.x;                       // 0..127
    int tid = threadIdx.x, w = tid >> 6, lane = tid & 63;
    float m = -3.4e38f, s = 0.f;
    for (int c = tid; c < CHUNK; c += 256) {
        float mm = pm[c * (BB * FOUT) + r], ss = ps[c * (BB * FOUT) + r];
        float M = fmaxf(m, mm);
        s = s * expf(m - M) + ss * expf(mm - M);
        m = M;
    }
    for (int o = 1; o < 64; o <<= 1) {
        float mm = __shfl_xor(m, o), ss = __shfl_xor(s, o);
        float M = fmaxf(m, mm);
        s = s * expf(m - M) + ss * expf(mm - M);
        m = M;
    }
    __shared__ float smx[4], ssm[4];
    if (lane == 0) { smx[w] = m; ssm[w] = s; }
    __syncthreads();
    if (tid == 0) {
        float M = fmaxf(fmaxf(smx[0], smx[1]), fmaxf(smx[2], smx[3]));
        float S = ssm[0] * expf(smx[0] - M) + ssm[1] * expf(smx[1] - M)
                + ssm[2] * expf(smx[2] - M) + ssm[3] * expf(smx[3] - M);
        lse[r] = M + logf(S);
    }
}

// ---------------------------------------------------------------------------
// K5: out = out2 - lse (broadcast per row), fully coalesced float4 pass.
// grid = BB*NN*FOUT/4/256 = 512 blocks.
__global__ __launch_bounds__(256)
void k_sub(const float* __restrict__ out2, const float* __restrict__ lse,
           float* __restrict__ out)
{
    int idx = blockIdx.x * 256 + threadIdx.x;      // float4 index
    float4 v = ((const float4*)out2)[idx];
    int f0 = idx * 4;
    int b = f0 >> 17;                              // NN*FOUT = 131072 floats/b
    int o = f0 & (FOUT - 1);                       // multiple of 4
    float4 l = *(const float4*)&lse[b * FOUT + o];
    float4 rv;
    rv.x = v.x - l.x; rv.y = v.y - l.y; rv.z = v.z - l.z; rv.w = v.w - l.w;
    ((float4*)out)[idx] = rv;
}

// ---------------------------------------------------------------------------
extern "C" void kernel_launch(void* const* d_in, const int* in_sizes, int n_in,
                              void* d_out, int out_size, void* d_ws, size_t ws_size,
                              hipStream_t stream)
{
    (void)n_in; (void)out_size; (void)ws_size;
    const float* x     = (const float*)d_in[0];
    const int*   edges = (const int*)d_in[1];
    const float* Wh    = (const float*)d_in[2];
    const float* ah    = (const float*)d_in[3];
    const float* bh    = (const float*)d_in[4];
    const float* Wo    = (const float*)d_in[5];
    const float* ao    = (const float*)d_in[6];
    const float* bo    = (const float*)d_in[7];
    int E = in_sizes[1] / 2;

    char* w = (char*)d_ws;
    float* h1   = (float*)w; w += (size_t)BB * NN * C1 * 4;        // 1 MB
    float* s1h  = (float*)w; w += (size_t)BB * NN * HH * 4;        // 128 KB
    float* s2h  = (float*)w; w += (size_t)BB * NN * HH * 4;        // 128 KB
    float* h2   = (float*)w; w += (size_t)BB * NN * FOUT * 4;      // 1 MB
    float* s1o  = (float*)w; w += (size_t)BB * NN * 4;
    float* s2o  = (float*)w; w += (size_t)BB * NN * 4;
    float* out2 = (float*)w; w += (size_t)BB * NN * FOUT * 4;      // 1 MB... 2 MB total
    float* pm   = (float*)w; w += (size_t)CHUNK * BB * FOUT * 4;   // 256 KB
    float* ps   = (float*)w; w += (size_t)CHUNK * BB * FOUT * 4;   // 256 KB
    float* lse  = (float*)w; w += 4096;                            // 512 B used
    int*   cnt  = (int*)w;   w += (size_t)NN * 4;
    int*   csr  = (int*)w;   w += (size_t)NN * MAXD * 4;           // 1.5 MB

    hipMemsetAsync(cnt, 0, (size_t)NN * 4, stream);

    int scatter_blocks = (E + 255) / 256;   // 128
    k_front <<<GB1 + scatter_blocks, 256, 0, stream>>>(x, Wh, ah, edges, E,
                                                       h1, s1h, s2h, cnt, csr);
    k_att1g2<<<BB * NN / 4, 256, 0, stream>>>(h1, s1h, s2h, bh, cnt, csr,
                                              Wo, ao, h2, s1o, s2o);
    k_att2b <<<BB * NN / 4, 256, 0, stream>>>(h2, s1o, s2o, bo, cnt, csr,
                                              out2, pm, ps);
    k_merge <<<BB * FOUT, 256, 0, stream>>>(pm, ps, lse);
    k_sub   <<<BB * NN * FOUT / 4 / 256, 256, 0, stream>>>(out2, lse, (float*)d_out);
}